// Round 20
// baseline (108.543 us; speedup 1.0000x reference)
//
#include <hip/hip_runtime.h>
#include <math.h>

#define N_IMG 128
#define C_DIM 128
#define K_CL  64
#define S_PIX 4096
#define PB    4                 // blocks per image
#define SPB   (S_PIX/PB)        // 1024 pixels per block
#define CHK   32                // pixels per chunk
#define NCHK  (SPB/CHK)         // 32
#define NBUF  4                 // X staging buffers (3-deep prefetch)

typedef __attribute__((ext_vector_type(8))) short bf16x8;
typedef __attribute__((ext_vector_type(4))) float f32x4;

__device__ __forceinline__ unsigned short f2bf_rn(float v) {
    unsigned u = __float_as_uint(v);
    unsigned r = u + 0x7fffu + ((u >> 16) & 1u);
    return (unsigned short)(r >> 16);
}
__device__ __forceinline__ float bf2f(unsigned short h) {
    return __uint_as_float(((unsigned)h) << 16);
}

// X-tile: row c = 32 floats = 128B = one bank period; 8 granules of 16B.
// Physical granule P = logical s-granule ^ sx(c).  sx(c)=(c&3)|((c&1)<<2).
__device__ __forceinline__ int sx(int c) { return ((c & 3) | ((c & 1) << 2)) & 7; }
// a'-tile: row k = 32 shorts = 64B; 4 granules of 16B. sa(k) = (k>>2)&3.
__device__ __forceinline__ int sa(int k) { return (k >> 2) & 3; }

// truncation hi/lo split of 8 floats -> two bf16x8, packed via v_perm
__device__ __forceinline__ void cvt8(const float* v, bf16x8& h, bf16x8& l) {
    union { unsigned w[4]; bf16x8 v8; } H, L;
    #pragma unroll
    for (int p = 0; p < 4; ++p) {
        unsigned u0 = __float_as_uint(v[2*p]);
        unsigned u1 = __float_as_uint(v[2*p+1]);
        float r0 = v[2*p]   - __uint_as_float(u0 & 0xffff0000u);
        float r1 = v[2*p+1] - __uint_as_float(u1 & 0xffff0000u);
        H.w[p] = __builtin_amdgcn_perm(u1, u0, 0x07060302u);
        L.w[p] = __builtin_amdgcn_perm(__float_as_uint(r1), __float_as_uint(r0), 0x07060302u);
    }
    h = H.v8; l = L.v8;
}

// async global->LDS, 16B per lane, lane writes ldsbase + lane*16 (linear)
__device__ __forceinline__ void gll16(const float* g, float* l) {
    __builtin_amdgcn_global_load_lds(
        (const __attribute__((address_space(1))) unsigned int*)(g),
        (__attribute__((address_space(3))) unsigned int*)(l),
        16, 0, 0);
}

// ---- kernel 0: fused clear (vlad 4MB + asum) AND W pre-fragmentation ----
__global__ void k_prep(const float* __restrict__ w, unsigned short* __restrict__ wf,
                       float4* __restrict__ out4, float4* __restrict__ asum4) {
    int i = blockIdx.x * 256 + threadIdx.x;
    f32x4 z = (f32x4)0.f;
    if (i < (N_IMG*K_CL*C_DIM)/4) out4[i] = *(float4*)&z;
    if (i < (N_IMG*K_CL)/4)       asum4[i] = *(float4*)&z;
    if (i < 8192) {
        int j = i & 7, l = (i >> 3) & 63, t = (i >> 9) & 3, m = (i >> 11) & 3;
        int k = 16*m + (l & 15);
        int c = 32*t + 4*j + (l >> 4);
        float v = w[k * C_DIM + c];
        unsigned short h = f2bf_rn(v);
        wf[i]        = h;
        wf[8192 + i] = f2bf_rn(v - bf2f(h));
    }
}

// ---- kernel 1: lockstep fused kernel, 4 waves, 2 blocks/CU, 2 barriers/chunk ----
__global__ __launch_bounds__(256, 1)
void k_main(const float* __restrict__ x,              // [N][C][S]
            const unsigned short* __restrict__ wf,    // [2][16][64][8] bf16 bits
            const float* __restrict__ bias,           // [K]
            float* __restrict__ vlad,                 // [N][K][C] accumulator (= d_out)
            float* __restrict__ asum)                 // [N][K]
{
    __shared__ float Xs[NBUF][C_DIM*CHK];             // 64KB: x chunk tiles, swizzled
    __shared__ unsigned short aS[2*K_CL*CHK];         // 8KB: u = e*rnorm, hi/lo planes
    __shared__ __align__(16) float redS[2][2][16];    // 256B: softmax half-sum exchange

    const int tid  = threadIdx.x;
    const int lane = tid & 63;
    const int wid  = tid >> 6;            // 0..3
    const int lc   = lane & 15;
    const int g    = lane >> 4;

    const int p  = wid & 1;               // phase A: px-tile (16 px)
    const int mh = wid >> 1;              // phase A: k-half (2 m-tiles)
    const int px = p*16 + lc;
    const int cq = wid * 32;              // phase B: c-slice

    const int n  = blockIdx.x / PB;       // n-major (lowest WRITE_SIZE empirically)
    const int sp = blockIdx.x % PB;
    const float* xn = x + (size_t)n * (C_DIM * S_PIX) + sp * SPB;

    const float LOG2E = 1.44269504f;

    // ---- W fragments for this wave's k-half into REGISTERS (anchored) ----
    bf16x8 Wh[2][4], Wl[2][4];
    #pragma unroll
    for (int mm = 0; mm < 2; ++mm)
        #pragma unroll
        for (int t = 0; t < 4; ++t) {
            int m = 2*mh + mm;
            Wh[mm][t] = *(const bf16x8*)&wf[((m*4 + t)*64 + lane)*8];
            Wl[mm][t] = *(const bf16x8*)&wf[((16 + m*4 + t)*64 + lane)*8];
        }
    #pragma unroll
    for (int mm = 0; mm < 2; ++mm)
        #pragma unroll
        for (int t = 0; t < 4; ++t) {
            asm volatile("" : "+v"(Wh[mm][t]));
            asm volatile("" : "+v"(Wl[mm][t]));
        }
    f32x4 bias_r[2];
    #pragma unroll
    for (int mm = 0; mm < 2; ++mm) {
        f32x4 b4 = *(const f32x4*)&bias[32*mh + 16*mm + 4*g];
        #pragma unroll
        for (int jj = 0; jj < 4; ++jj) bias_r[mm][jj] = b4[jj] * LOG2E;  // exp2 fold
    }

    f32x4 accV[4][2];
    #pragma unroll
    for (int m = 0; m < 4; ++m) { accV[m][0] = (f32x4)0.f; accV[m][1] = (f32x4)0.f; }
    float asum_acc[8];
    #pragma unroll
    for (int i = 0; i < 8; ++i) asum_acc[i] = 0.f;

    // per-lane constant addressing
    const int eA  = g*32 + (((px >> 2) ^ sx(g)) << 2) + (px & 3);  // A-read base
    const int sxB = sx(lc);                                        // B-read sx(c)
    const int saB = sa(lc);                                        // B a'-read sa part
    const int ps  = g >> 1;                                        // redS p for lane's s
    const int sb  = (8*g) & 15;                                    // redS base index

    // stage chunk t into Xbuf: wave stages rows wid*32..+31 (4 gll16, 8 rows each)
    auto STAGE = [&](int t, float* Xbuf) {
        #pragma unroll
        for (int i2 = 0; i2 < 4; ++i2) {
            int rowblk = wid*32 + i2*8;
            int row = rowblk + (lane >> 3);
            const float* gp = xn + (size_t)row * S_PIX + t*CHK
                            + 4*((lane & 7) ^ sx(row));
            gll16(gp, &Xbuf[rowblk * 32]);
        }
    };

    // ---- prologue: 3-deep prefetch ----
    STAGE(0, Xs[0]);
    STAGE(1, Xs[1]);
    STAGE(2, Xs[2]);
    asm volatile("s_waitcnt vmcnt(8)" ::: "memory");   // chunk 0 landed
    __builtin_amdgcn_s_barrier();
    __builtin_amdgcn_sched_barrier(0);

    for (int ch = 0; ch < NCHK; ++ch) {
        float* Xb = Xs[ch & (NBUF-1)];

        // fire-and-forget stage of chunk ch+3
        if (ch + 3 < NCHK) STAGE(ch + 3, Xs[(ch + 3) & (NBUF-1)]);

        // ============ Phase A: GEMM1 (2 m-tiles) + softmax partials ============
        float s0 = 0.f, s1 = 0.f, s2 = 0.f, s3 = 0.f;   // 4 indep sumsq chains
        f32x4 accL[2];
        accL[0] = (f32x4)0.f; accL[1] = (f32x4)0.f;
        __builtin_amdgcn_s_setprio(1);                   // favor MFMA-issuing wave
        #pragma unroll
        for (int t = 0; t < 4; ++t) {
            float xv[8];
            #pragma unroll
            for (int j = 0; j < 8; ++j)
                xv[j] = Xb[eA + 1024*t + 128*j];     // c = 32t+4j+g, swizzle folded
            s0 = fmaf(xv[0], xv[0], s0); s1 = fmaf(xv[1], xv[1], s1);
            s2 = fmaf(xv[2], xv[2], s2); s3 = fmaf(xv[3], xv[3], s3);
            s0 = fmaf(xv[4], xv[4], s0); s1 = fmaf(xv[5], xv[5], s1);
            s2 = fmaf(xv[6], xv[6], s2); s3 = fmaf(xv[7], xv[7], s3);
            bf16x8 xh, xl;
            cvt8(xv, xh, xl);
            #pragma unroll
            for (int mm = 0; mm < 2; ++mm) {
                accL[mm] = __builtin_amdgcn_mfma_f32_16x16x32_bf16(Wh[mm][t], xh, accL[mm], 0,0,0);
                accL[mm] = __builtin_amdgcn_mfma_f32_16x16x32_bf16(Wh[mm][t], xl, accL[mm], 0,0,0);
                accL[mm] = __builtin_amdgcn_mfma_f32_16x16x32_bf16(Wl[mm][t], xh, accL[mm], 0,0,0);
            }
        }
        __builtin_amdgcn_s_setprio(0);
        float ss = (s0 + s1) + (s2 + s3);
        ss += __shfl_xor(ss, 16); ss += __shfl_xor(ss, 32);
        float rnorm = 1.0f / fmaxf(sqrtf(ss), 1e-12f);
        float rn2 = rnorm * LOG2E;                      // exp2 fold

        // no-max softmax partials (logits bounded: |dot|<=~1.15, |b|<=0.5)
        float e[8]; float sm = 0.f;
        #pragma unroll
        for (int mm = 0; mm < 2; ++mm)
            #pragma unroll
            for (int jj = 0; jj < 4; ++jj) {
                float t2 = exp2f(fmaf(accL[mm][jj], rn2, bias_r[mm][jj]));
                e[mm*4+jj] = t2;
                sm += t2;
            }
        sm += __shfl_xor(sm, 16); sm += __shfl_xor(sm, 32);
        if (g == 0) redS[p][mh][lc] = sm;

        // u = e * rnorm (UNSCALED by coef) -> hi/lo bf16 -> swizzled aS
        #pragma unroll
        for (int mm = 0; mm < 2; ++mm)
            #pragma unroll
            for (int jj = 0; jj < 4; ++jj) {
                float ap = e[mm*4+jj] * rnorm;
                unsigned u = __float_as_uint(ap);
                float r = ap - __uint_as_float(u & 0xffff0000u);
                int k  = 32*mh + 16*mm + 4*g + jj;     // sa(k)=g
                int ix = k*32 + (((px >> 3) ^ g) << 3) + (px & 7);
                aS[ix]        = (unsigned short)(u >> 16);
                aS[2048 + ix] = (unsigned short)(__float_as_uint(r) >> 16);
            }

        // ---- MID: redS + aS ready (LDS flush only, DMA stays in flight) ----
        asm volatile("s_waitcnt lgkmcnt(0)" ::: "memory");
        __builtin_amdgcn_s_barrier();
        __builtin_amdgcn_sched_barrier(0);

        // A-side epilogue: asum with exact coef (sibling half-sum now visible)
        {
            float S = sm + redS[p][mh^1][lc];
            float coef = __builtin_amdgcn_rcpf(S);
            #pragma unroll
            for (int i = 0; i < 8; ++i) asum_acc[i] = fmaf(e[i], coef, asum_acc[i]);
        }

        // ============ Phase B: GEMM2 (wave's 32-c slice, K=32) ============
        {
            // coef[s] for this lane's 8 kdim positions s = 8g..8g+7
            float4 u0 = *(const float4*)&redS[ps][0][sb];
            float4 u1 = *(const float4*)&redS[ps][0][sb+4];
            float4 v0 = *(const float4*)&redS[ps][1][sb];
            float4 v1 = *(const float4*)&redS[ps][1][sb+4];
            float cf[8] = {u0.x+v0.x, u0.y+v0.y, u0.z+v0.z, u0.w+v0.w,
                           u1.x+v1.x, u1.y+v1.y, u1.z+v1.z, u1.w+v1.w};
            #pragma unroll
            for (int j = 0; j < 8; ++j) cf[j] = __builtin_amdgcn_rcpf(cf[j]);

            bf16x8 Ah[4], Al[4];
            #pragma unroll
            for (int m = 0; m < 4; ++m) {
                int off = (16*m + lc)*32 + ((g ^ saB) << 3);
                Ah[m] = *(const bf16x8*)&aS[off];
                Al[m] = *(const bf16x8*)&aS[2048 + off];
            }
            __builtin_amdgcn_s_setprio(1);               // favor MFMA-issuing wave
            #pragma unroll
            for (int nn = 0; nn < 2; ++nn) {
                int c  = cq + nn*16 + lc;
                int P0 = (2*g) ^ sxB;
                float4 f0 = *(const float4*)&Xb[c*32 + P0*4];
                float4 f1 = *(const float4*)&Xb[c*32 + (P0 ^ 1)*4];
                float xv[8] = {f0.x*cf[0], f0.y*cf[1], f0.z*cf[2], f0.w*cf[3],
                               f1.x*cf[4], f1.y*cf[5], f1.z*cf[6], f1.w*cf[7]};
                bf16x8 xh, xl;
                cvt8(xv, xh, xl);
                #pragma unroll
                for (int m = 0; m < 4; ++m) {
                    accV[m][nn] = __builtin_amdgcn_mfma_f32_16x16x32_bf16(Ah[m], xh, accV[m][nn], 0,0,0);
                    accV[m][nn] = __builtin_amdgcn_mfma_f32_16x16x32_bf16(Ah[m], xl, accV[m][nn], 0,0,0);
                    accV[m][nn] = __builtin_amdgcn_mfma_f32_16x16x32_bf16(Al[m], xh, accV[m][nn], 0,0,0);
                }
            }
            __builtin_amdgcn_s_setprio(0);
        }

        // ---- END: chunk ch+1 landed (counted, never over-drain); aS released ----
        if (ch + 1 < NCHK) {
            if (ch + 3 < NCHK)
                asm volatile("s_waitcnt vmcnt(8) lgkmcnt(0)" ::: "memory");
            else if (ch + 2 < NCHK)
                asm volatile("s_waitcnt vmcnt(4) lgkmcnt(0)" ::: "memory");
            else
                asm volatile("s_waitcnt vmcnt(0) lgkmcnt(0)" ::: "memory");
            __builtin_amdgcn_s_barrier();
            __builtin_amdgcn_sched_barrier(0);
        }
    }

    // ---- epilogue: vlad partials -> global atomics ----
    float* vb = vlad + (size_t)n * (K_CL * C_DIM);
    #pragma unroll
    for (int m = 0; m < 4; ++m)
        #pragma unroll
        for (int nn = 0; nn < 2; ++nn)
            #pragma unroll
            for (int jj = 0; jj < 4; ++jj)
                atomicAdd(&vb[(16*m + 4*g + jj)*C_DIM + cq + nn*16 + lc],
                          accV[m][nn][jj]);

    // ---- asum: butterfly over lc (wave's 16 px), then atomics ----
    #pragma unroll
    for (int i = 0; i < 8; ++i) {
        float v = asum_acc[i];
        v += __shfl_xor(v, 1); v += __shfl_xor(v, 2);
        v += __shfl_xor(v, 4); v += __shfl_xor(v, 8);
        asum_acc[i] = v;
    }
    if (lc == 0) {
        #pragma unroll
        for (int mm = 0; mm < 2; ++mm)
            #pragma unroll
            for (int jj = 0; jj < 4; ++jj)
                atomicAdd(&asum[n*K_CL + 32*mh + 16*mm + 4*g + jj], asum_acc[mm*4+jj]);
    }
}

// ---- kernel 2: subtract a-sum*centroid, intra-norm, global norm (float4) ----
__global__ __launch_bounds__(256)
void k_final(float* __restrict__ vlad,          // [N][K*C] in/out (= d_out)
             const float* __restrict__ asum,    // [N][K]
             const float* __restrict__ cent)    // [K][C]
{
    __shared__ float v[K_CL * 132];             // 132-stride: 16B-aligned float4 rows
    __shared__ float red[K_CL][4];
    __shared__ float rin[K_CL];
    __shared__ float rtot_s;
    const int tid = threadIdx.x;
    const int n   = blockIdx.x;
    float* vb = vlad + (size_t)n * (K_CL * C_DIM);
    const float* as = asum + n * K_CL;

    // vectorized: 2048 float4s, 8 per thread
    for (int i4 = tid; i4 < (K_CL*C_DIM)/4; i4 += 256) {
        int k = i4 >> 5, c4 = i4 & 31;          // c = 4*c4
        float4 a = *(const float4*)&vb[i4*4];
        float4 b = *(const float4*)&cent[i4*4];
        float ak = as[k];
        float4 r; r.x = a.x - ak*b.x; r.y = a.y - ak*b.y;
                  r.z = a.z - ak*b.z; r.w = a.w - ak*b.w;
        *(float4*)&v[k*132 + c4*4] = r;
    }
    __syncthreads();
    {
        int k = tid >> 2, p = tid & 3;
        float s2 = 0.f;
        #pragma unroll
        for (int u = 0; u < 32; ++u) { float t = v[k*132 + (u<<2) + p]; s2 = fmaf(t, t, s2); }
        red[k][p] = s2;
    }
    __syncthreads();
    if (tid < K_CL) {
        float s2 = red[tid][0] + red[tid][1] + red[tid][2] + red[tid][3];
        float r  = 1.0f / fmaxf(sqrtf(s2), 1e-12f);
        rin[tid] = r;
        red[tid][0] = s2 * r * r;
    }
    __syncthreads();
    if (tid < 64) {
        float t = red[tid][0];
        t += __shfl_xor(t, 32); t += __shfl_xor(t, 16); t += __shfl_xor(t, 8);
        t += __shfl_xor(t, 4);  t += __shfl_xor(t, 2);  t += __shfl_xor(t, 1);
        if (tid == 0) rtot_s = 1.0f / fmaxf(sqrtf(t), 1e-12f);
    }
    __syncthreads();
    float rt = rtot_s;
    for (int i4 = tid; i4 < (K_CL*C_DIM)/4; i4 += 256) {
        int k = i4 >> 5, c4 = i4 & 31;
        float4 a = *(const float4*)&v[k*132 + c4*4];
        float s = rin[k] * rt;
        float4 r; r.x = a.x*s; r.y = a.y*s; r.z = a.z*s; r.w = a.w*s;
        *(float4*)&vb[i4*4] = r;
    }
}

extern "C" void kernel_launch(void* const* d_in, const int* in_sizes, int n_in,
                              void* d_out, int out_size, void* d_ws, size_t ws_size,
                              hipStream_t stream) {
    const float* x    = (const float*)d_in[0];
    const float* w    = (const float*)d_in[1];
    const float* b    = (const float*)d_in[2];
    const float* cent = (const float*)d_in[3];
    float* out = (float*)d_out;
    unsigned short* wf = (unsigned short*)d_ws;           // 32KB
    float* asum = (float*)((char*)d_ws + 32768);          // [N][K]

    k_prep<<<(N_IMG*K_CL*C_DIM/4 + 255)/256, 256, 0, stream>>>(
        w, wf, (float4*)out, (float4*)asum);
    k_main<<<N_IMG * PB, 256, 0, stream>>>(x, wf, b, out, asum);
    k_final<<<N_IMG, 256, 0, stream>>>(out, asum, cent);
}

// Round 21
// 105.088 us; speedup vs baseline: 1.0329x; 1.0329x over previous
//
#include <hip/hip_runtime.h>
#include <math.h>

#define N_IMG 128
#define C_DIM 128
#define K_CL  64
#define S_PIX 4096
#define PB    4                 // blocks per image
#define SPB   (S_PIX/PB)        // 1024 pixels per block
#define CHK   32                // pixels per chunk
#define NCHK  (SPB/CHK)         // 32
#define NBUF  4                 // X staging buffers (3-deep prefetch)

typedef __attribute__((ext_vector_type(8))) short bf16x8;
typedef __attribute__((ext_vector_type(4))) float f32x4;

__device__ __forceinline__ unsigned short f2bf_rn(float v) {
    unsigned u = __float_as_uint(v);
    unsigned r = u + 0x7fffu + ((u >> 16) & 1u);
    return (unsigned short)(r >> 16);
}
__device__ __forceinline__ float bf2f(unsigned short h) {
    return __uint_as_float(((unsigned)h) << 16);
}

// X-tile: row c = 32 floats = 128B = one bank period; 8 granules of 16B.
// Physical granule P = logical s-granule ^ sx(c).  sx(c)=(c&3)|((c&1)<<2).
__device__ __forceinline__ int sx(int c) { return ((c & 3) | ((c & 1) << 2)) & 7; }
// a'-tile: row k = 32 shorts = 64B; 4 granules of 16B. sa(k) = (k>>2)&3.
__device__ __forceinline__ int sa(int k) { return (k >> 2) & 3; }

// truncation hi/lo split of 8 floats -> two bf16x8, packed via v_perm
__device__ __forceinline__ void cvt8(const float* v, bf16x8& h, bf16x8& l) {
    union { unsigned w[4]; bf16x8 v8; } H, L;
    #pragma unroll
    for (int p = 0; p < 4; ++p) {
        unsigned u0 = __float_as_uint(v[2*p]);
        unsigned u1 = __float_as_uint(v[2*p+1]);
        float r0 = v[2*p]   - __uint_as_float(u0 & 0xffff0000u);
        float r1 = v[2*p+1] - __uint_as_float(u1 & 0xffff0000u);
        H.w[p] = __builtin_amdgcn_perm(u1, u0, 0x07060302u);
        L.w[p] = __builtin_amdgcn_perm(__float_as_uint(r1), __float_as_uint(r0), 0x07060302u);
    }
    h = H.v8; l = L.v8;
}

// async global->LDS, 16B per lane, lane writes ldsbase + lane*16 (linear)
__device__ __forceinline__ void gll16(const float* g, float* l) {
    __builtin_amdgcn_global_load_lds(
        (const __attribute__((address_space(1))) unsigned int*)(g),
        (__attribute__((address_space(3))) unsigned int*)(l),
        16, 0, 0);
}

// ---- kernel 0: fused clear (vlad 4MB + asum) AND W pre-fragmentation ----
__global__ void k_prep(const float* __restrict__ w, unsigned short* __restrict__ wf,
                       float4* __restrict__ out4, float4* __restrict__ asum4) {
    int i = blockIdx.x * 256 + threadIdx.x;
    f32x4 z = (f32x4)0.f;
    if (i < (N_IMG*K_CL*C_DIM)/4) out4[i] = *(float4*)&z;
    if (i < (N_IMG*K_CL)/4)       asum4[i] = *(float4*)&z;
    if (i < 8192) {
        int j = i & 7, l = (i >> 3) & 63, t = (i >> 9) & 3, m = (i >> 11) & 3;
        int k = 16*m + (l & 15);
        int c = 32*t + 4*j + (l >> 4);
        float v = w[k * C_DIM + c];
        unsigned short h = f2bf_rn(v);
        wf[i]        = h;
        wf[8192 + i] = f2bf_rn(v - bf2f(h));
    }
}

// ---- kernel 1: lockstep fused kernel, 4 waves, 2 blocks/CU, 2 barriers/chunk ----
// co-resident blocks (b, b+256) process chunks with a half-range stagger so
// their barrier stalls decorrelate (cross-block gap filling).
__global__ __launch_bounds__(256, 1)
void k_main(const float* __restrict__ x,              // [N][C][S]
            const unsigned short* __restrict__ wf,    // [2][16][64][8] bf16 bits
            const float* __restrict__ bias,           // [K]
            float* __restrict__ vlad,                 // [N][K][C] accumulator (= d_out)
            float* __restrict__ asum)                 // [N][K]
{
    __shared__ float Xs[NBUF][C_DIM*CHK];             // 64KB: x chunk tiles, swizzled
    __shared__ unsigned short aS[2*K_CL*CHK];         // 8KB: u = e*rnorm, hi/lo planes
    __shared__ __align__(16) float redS[2][2][16];    // 256B: softmax half-sum exchange

    const int tid  = threadIdx.x;
    const int lane = tid & 63;
    const int wid  = tid >> 6;            // 0..3
    const int lc   = lane & 15;
    const int g    = lane >> 4;

    const int p  = wid & 1;               // phase A: px-tile (16 px)
    const int mh = wid >> 1;              // phase A: k-half (2 m-tiles)
    const int px = p*16 + lc;
    const int cq = wid * 32;              // phase B: c-slice

    const int n  = blockIdx.x / PB;       // n-major (lowest WRITE_SIZE empirically)
    const int sp = blockIdx.x % PB;
    const float* xn = x + (size_t)n * (C_DIM * S_PIX) + sp * SPB;

    // chunk-order stagger: likely co-resident pair (b, b+256) -> opposite halves
    const int coff = ((blockIdx.x >> 8) & 1) * (NCHK / 2);

    // ---- W fragments for this wave's k-half into REGISTERS (anchored) ----
    bf16x8 Wh[2][4], Wl[2][4];
    #pragma unroll
    for (int mm = 0; mm < 2; ++mm)
        #pragma unroll
        for (int t = 0; t < 4; ++t) {
            int m = 2*mh + mm;
            Wh[mm][t] = *(const bf16x8*)&wf[((m*4 + t)*64 + lane)*8];
            Wl[mm][t] = *(const bf16x8*)&wf[((16 + m*4 + t)*64 + lane)*8];
        }
    #pragma unroll
    for (int mm = 0; mm < 2; ++mm)
        #pragma unroll
        for (int t = 0; t < 4; ++t) {
            asm volatile("" : "+v"(Wh[mm][t]));
            asm volatile("" : "+v"(Wl[mm][t]));
        }
    f32x4 bias_r[2];
    #pragma unroll
    for (int mm = 0; mm < 2; ++mm)
        bias_r[mm] = *(const f32x4*)&bias[32*mh + 16*mm + 4*g];

    f32x4 accV[4][2];
    #pragma unroll
    for (int m = 0; m < 4; ++m) { accV[m][0] = (f32x4)0.f; accV[m][1] = (f32x4)0.f; }
    float asum_acc[8];
    #pragma unroll
    for (int i = 0; i < 8; ++i) asum_acc[i] = 0.f;

    // per-lane constant addressing
    const int eA  = g*32 + (((px >> 2) ^ sx(g)) << 2) + (px & 3);  // A-read base
    const int sxB = sx(lc);                                        // B-read sx(c)
    const int saB = sa(lc);                                        // B a'-read sa part
    const int ps  = g >> 1;                                        // redS p for lane's s
    const int sb  = (8*g) & 15;                                    // redS base index

    // stage logical chunk t (staggered) into Xbuf: wave stages rows wid*32..+31
    auto STAGE = [&](int t, float* Xbuf) {
        int chs = (t + coff) & (NCHK - 1);
        #pragma unroll
        for (int i2 = 0; i2 < 4; ++i2) {
            int rowblk = wid*32 + i2*8;
            int row = rowblk + (lane >> 3);
            const float* gp = xn + (size_t)row * S_PIX + chs*CHK
                            + 4*((lane & 7) ^ sx(row));
            gll16(gp, &Xbuf[rowblk * 32]);
        }
    };

    // ---- prologue: 3-deep prefetch ----
    STAGE(0, Xs[0]);
    STAGE(1, Xs[1]);
    STAGE(2, Xs[2]);
    asm volatile("s_waitcnt vmcnt(8)" ::: "memory");   // chunk 0 landed
    __builtin_amdgcn_s_barrier();
    __builtin_amdgcn_sched_barrier(0);

    for (int ch = 0; ch < NCHK; ++ch) {
        float* Xb = Xs[ch & (NBUF-1)];

        // fire-and-forget stage of chunk ch+3
        if (ch + 3 < NCHK) STAGE(ch + 3, Xs[(ch + 3) & (NBUF-1)]);

        // ============ Phase A: GEMM1 (2 m-tiles) + softmax partials ============
        float s0 = 0.f, s1 = 0.f, s2 = 0.f, s3 = 0.f;   // 4 indep sumsq chains
        f32x4 accL[2];
        accL[0] = (f32x4)0.f; accL[1] = (f32x4)0.f;
        #pragma unroll
        for (int t = 0; t < 4; ++t) {
            float xv[8];
            #pragma unroll
            for (int j = 0; j < 8; ++j)
                xv[j] = Xb[eA + 1024*t + 128*j];     // c = 32t+4j+g, swizzle folded
            s0 = fmaf(xv[0], xv[0], s0); s1 = fmaf(xv[1], xv[1], s1);
            s2 = fmaf(xv[2], xv[2], s2); s3 = fmaf(xv[3], xv[3], s3);
            s0 = fmaf(xv[4], xv[4], s0); s1 = fmaf(xv[5], xv[5], s1);
            s2 = fmaf(xv[6], xv[6], s2); s3 = fmaf(xv[7], xv[7], s3);
            bf16x8 xh, xl;
            cvt8(xv, xh, xl);
            #pragma unroll
            for (int mm = 0; mm < 2; ++mm) {
                accL[mm] = __builtin_amdgcn_mfma_f32_16x16x32_bf16(Wh[mm][t], xh, accL[mm], 0,0,0);
                accL[mm] = __builtin_amdgcn_mfma_f32_16x16x32_bf16(Wh[mm][t], xl, accL[mm], 0,0,0);
                accL[mm] = __builtin_amdgcn_mfma_f32_16x16x32_bf16(Wl[mm][t], xh, accL[mm], 0,0,0);
            }
        }
        float ss = (s0 + s1) + (s2 + s3);
        ss += __shfl_xor(ss, 16); ss += __shfl_xor(ss, 32);
        float rnorm = 1.0f / fmaxf(sqrtf(ss), 1e-12f);

        // no-max softmax partials (logits bounded: |dot|<=~1.15, |b|<=0.5)
        float e[8]; float sm = 0.f;
        #pragma unroll
        for (int mm = 0; mm < 2; ++mm)
            #pragma unroll
            for (int jj = 0; jj < 4; ++jj) {
                float t2 = __expf(fmaf(accL[mm][jj], rnorm, bias_r[mm][jj]));
                e[mm*4+jj] = t2;
                sm += t2;
            }
        sm += __shfl_xor(sm, 16); sm += __shfl_xor(sm, 32);
        if (g == 0) redS[p][mh][lc] = sm;

        // u = e * rnorm (UNSCALED by coef) -> hi/lo bf16 -> swizzled aS
        #pragma unroll
        for (int mm = 0; mm < 2; ++mm)
            #pragma unroll
            for (int jj = 0; jj < 4; ++jj) {
                float ap = e[mm*4+jj] * rnorm;
                unsigned u = __float_as_uint(ap);
                float r = ap - __uint_as_float(u & 0xffff0000u);
                int k  = 32*mh + 16*mm + 4*g + jj;     // sa(k)=g
                int ix = k*32 + (((px >> 3) ^ g) << 3) + (px & 7);
                aS[ix]        = (unsigned short)(u >> 16);
                aS[2048 + ix] = (unsigned short)(__float_as_uint(r) >> 16);
            }

        // ---- MID: redS + aS ready (LDS flush only, DMA stays in flight) ----
        asm volatile("s_waitcnt lgkmcnt(0)" ::: "memory");
        __builtin_amdgcn_s_barrier();
        __builtin_amdgcn_sched_barrier(0);

        // A-side epilogue: asum with exact coef (sibling half-sum now visible)
        {
            float S = sm + redS[p][mh^1][lc];
            float coef = __builtin_amdgcn_rcpf(S);
            #pragma unroll
            for (int i = 0; i < 8; ++i) asum_acc[i] = fmaf(e[i], coef, asum_acc[i]);
        }

        // ============ Phase B: GEMM2 (wave's 32-c slice, K=32) ============
        {
            // coef[s] for this lane's 8 kdim positions s = 8g..8g+7
            float4 u0 = *(const float4*)&redS[ps][0][sb];
            float4 u1 = *(const float4*)&redS[ps][0][sb+4];
            float4 v0 = *(const float4*)&redS[ps][1][sb];
            float4 v1 = *(const float4*)&redS[ps][1][sb+4];
            float cf[8] = {u0.x+v0.x, u0.y+v0.y, u0.z+v0.z, u0.w+v0.w,
                           u1.x+v1.x, u1.y+v1.y, u1.z+v1.z, u1.w+v1.w};
            #pragma unroll
            for (int j = 0; j < 8; ++j) cf[j] = __builtin_amdgcn_rcpf(cf[j]);

            bf16x8 Ah[4], Al[4];
            #pragma unroll
            for (int m = 0; m < 4; ++m) {
                int off = (16*m + lc)*32 + ((g ^ saB) << 3);
                Ah[m] = *(const bf16x8*)&aS[off];
                Al[m] = *(const bf16x8*)&aS[2048 + off];
            }
            #pragma unroll
            for (int nn = 0; nn < 2; ++nn) {
                int c  = cq + nn*16 + lc;
                int P0 = (2*g) ^ sxB;
                float4 f0 = *(const float4*)&Xb[c*32 + P0*4];
                float4 f1 = *(const float4*)&Xb[c*32 + (P0 ^ 1)*4];
                float xv[8] = {f0.x*cf[0], f0.y*cf[1], f0.z*cf[2], f0.w*cf[3],
                               f1.x*cf[4], f1.y*cf[5], f1.z*cf[6], f1.w*cf[7]};
                bf16x8 xh, xl;
                cvt8(xv, xh, xl);
                #pragma unroll
                for (int m = 0; m < 4; ++m) {
                    accV[m][nn] = __builtin_amdgcn_mfma_f32_16x16x32_bf16(Ah[m], xh, accV[m][nn], 0,0,0);
                    accV[m][nn] = __builtin_amdgcn_mfma_f32_16x16x32_bf16(Ah[m], xl, accV[m][nn], 0,0,0);
                    accV[m][nn] = __builtin_amdgcn_mfma_f32_16x16x32_bf16(Al[m], xh, accV[m][nn], 0,0,0);
                }
            }
        }

        // ---- END: chunk ch+1 landed (counted, never over-drain); aS released ----
        if (ch + 1 < NCHK) {
            if (ch + 3 < NCHK)
                asm volatile("s_waitcnt vmcnt(8) lgkmcnt(0)" ::: "memory");
            else if (ch + 2 < NCHK)
                asm volatile("s_waitcnt vmcnt(4) lgkmcnt(0)" ::: "memory");
            else
                asm volatile("s_waitcnt vmcnt(0) lgkmcnt(0)" ::: "memory");
            __builtin_amdgcn_s_barrier();
            __builtin_amdgcn_sched_barrier(0);
        }
    }

    // ---- epilogue: vlad partials -> global atomics ----
    float* vb = vlad + (size_t)n * (K_CL * C_DIM);
    #pragma unroll
    for (int m = 0; m < 4; ++m)
        #pragma unroll
        for (int nn = 0; nn < 2; ++nn)
            #pragma unroll
            for (int jj = 0; jj < 4; ++jj)
                atomicAdd(&vb[(16*m + 4*g + jj)*C_DIM + cq + nn*16 + lc],
                          accV[m][nn][jj]);

    // ---- asum: butterfly over lc (wave's 16 px), then atomics ----
    #pragma unroll
    for (int i = 0; i < 8; ++i) {
        float v = asum_acc[i];
        v += __shfl_xor(v, 1); v += __shfl_xor(v, 2);
        v += __shfl_xor(v, 4); v += __shfl_xor(v, 8);
        asum_acc[i] = v;
    }
    if (lc == 0) {
        #pragma unroll
        for (int mm = 0; mm < 2; ++mm)
            #pragma unroll
            for (int jj = 0; jj < 4; ++jj)
                atomicAdd(&asum[n*K_CL + 32*mh + 16*mm + 4*g + jj], asum_acc[mm*4+jj]);
    }
}

// ---- kernel 2: subtract a-sum*centroid, intra-norm, global norm (float4) ----
__global__ __launch_bounds__(256)
void k_final(float* __restrict__ vlad,          // [N][K*C] in/out (= d_out)
             const float* __restrict__ asum,    // [N][K]
             const float* __restrict__ cent)    // [K][C]
{
    __shared__ float v[K_CL * 132];             // 132-stride: 16B-aligned float4 rows
    __shared__ float red[K_CL][4];
    __shared__ float rin[K_CL];
    __shared__ float rtot_s;
    const int tid = threadIdx.x;
    const int n   = blockIdx.x;
    float* vb = vlad + (size_t)n * (K_CL * C_DIM);
    const float* as = asum + n * K_CL;

    // vectorized: 2048 float4s, 8 per thread
    for (int i4 = tid; i4 < (K_CL*C_DIM)/4; i4 += 256) {
        int k = i4 >> 5, c4 = i4 & 31;          // c = 4*c4
        float4 a = *(const float4*)&vb[i4*4];
        float4 b = *(const float4*)&cent[i4*4];
        float ak = as[k];
        float4 r; r.x = a.x - ak*b.x; r.y = a.y - ak*b.y;
                  r.z = a.z - ak*b.z; r.w = a.w - ak*b.w;
        *(float4*)&v[k*132 + c4*4] = r;
    }
    __syncthreads();
    {
        int k = tid >> 2, p = tid & 3;
        float s2 = 0.f;
        #pragma unroll
        for (int u = 0; u < 32; ++u) { float t = v[k*132 + (u<<2) + p]; s2 = fmaf(t, t, s2); }
        red[k][p] = s2;
    }
    __syncthreads();
    if (tid < K_CL) {
        float s2 = red[tid][0] + red[tid][1] + red[tid][2] + red[tid][3];
        float r  = 1.0f / fmaxf(sqrtf(s2), 1e-12f);
        rin[tid] = r;
        red[tid][0] = s2 * r * r;
    }
    __syncthreads();
    if (tid < 64) {
        float t = red[tid][0];
        t += __shfl_xor(t, 32); t += __shfl_xor(t, 16); t += __shfl_xor(t, 8);
        t += __shfl_xor(t, 4);  t += __shfl_xor(t, 2);  t += __shfl_xor(t, 1);
        if (tid == 0) rtot_s = 1.0f / fmaxf(sqrtf(t), 1e-12f);
    }
    __syncthreads();
    float rt = rtot_s;
    for (int i4 = tid; i4 < (K_CL*C_DIM)/4; i4 += 256) {
        int k = i4 >> 5, c4 = i4 & 31;
        float4 a = *(const float4*)&v[k*132 + c4*4];
        float s = rin[k] * rt;
        float4 r; r.x = a.x*s; r.y = a.y*s; r.z = a.z*s; r.w = a.w*s;
        *(float4*)&vb[i4*4] = r;
    }
}

extern "C" void kernel_launch(void* const* d_in, const int* in_sizes, int n_in,
                              void* d_out, int out_size, void* d_ws, size_t ws_size,
                              hipStream_t stream) {
    const float* x    = (const float*)d_in[0];
    const float* w    = (const float*)d_in[1];
    const float* b    = (const float*)d_in[2];
    const float* cent = (const float*)d_in[3];
    float* out = (float*)d_out;
    unsigned short* wf = (unsigned short*)d_ws;           // 32KB
    float* asum = (float*)((char*)d_ws + 32768);          // [N][K]

    k_prep<<<(N_IMG*K_CL*C_DIM/4 + 255)/256, 256, 0, stream>>>(
        w, wf, (float4*)out, (float4*)asum);
    k_main<<<N_IMG * PB, 256, 0, stream>>>(x, wf, b, out, asum);
    k_final<<<N_IMG, 256, 0, stream>>>(out, asum, cent);
}